// Round 10
// baseline (355.815 us; speedup 1.0000x reference)
//
#include <hip/hip_runtime.h>
#include <math.h>

#define NN 50000
#define EE 800000
#define ET (EE + NN)      // edges + self loops
#define F_IN 128
#define HEADS 8
#define HID 16
#define C1 (HEADS * HID)  // 128
#define CLASSES 40
#define NEG_SLOPE 0.2f

typedef __attribute__((ext_vector_type(8))) short bf16x8;
typedef __attribute__((ext_vector_type(4))) float f32x4;

__device__ __forceinline__ unsigned short f2bf(float f) {
    unsigned u = __float_as_uint(f);
    unsigned r = (u + 0x7fffu + ((u >> 16) & 1u)) >> 16;  // round-to-nearest-even
    return (unsigned short)r;
}
__device__ __forceinline__ float lrelu(float a) {
    return (a > 0.f) ? a : NEG_SLOPE * a;
}
__device__ __forceinline__ float bflo(unsigned u) { return __uint_as_float(u << 16); }
__device__ __forceinline__ float bfhi(unsigned u) { return __uint_as_float(u & 0xffff0000u); }

// ---------------- GEMM1 (MFMA bf16) + fused elogit1 ----------------
// h1t layout: [HEADS][NN][HID] bf16. es_t/ed_t: [HEADS][NN] fp32.
// Wave w owns cols 32w..32w+31 = heads 2w (acc0) and 2w+1 (acc1) exactly.
__global__ void gemm1_kernel(const float* __restrict__ x, const float* __restrict__ W1,
                             const float* __restrict__ a_src, const float* __restrict__ a_dst,
                             unsigned short* __restrict__ h1t,
                             float* __restrict__ es_t, float* __restrict__ ed_t) {
    const int tid = threadIdx.x;
    const int w = tid >> 6, lane = tid & 63;
    const int q = lane >> 4, c = lane & 15;
    const int h0 = 2 * w, h1 = 2 * w + 1;

    bf16x8 bfrag[2][4];
    #pragma unroll
    for (int nt = 0; nt < 2; ++nt) {
        const int col = w * 32 + nt * 16 + c;
        #pragma unroll
        for (int kc = 0; kc < 4; ++kc) {
            const int k0 = kc * 32 + q * 8;
            bf16x8 bb;
            #pragma unroll
            for (int j = 0; j < 8; ++j)
                bb[j] = (short)f2bf(W1[(size_t)(k0 + j) * C1 + col]);
            bfrag[nt][kc] = bb;
        }
    }
    const float as0 = a_src[h0 * HID + c], as1 = a_src[h1 * HID + c];
    const float ad0 = a_dst[h0 * HID + c], ad1 = a_dst[h1 * HID + c];

    #pragma unroll
    for (int mt = 0; mt < 2; ++mt) {
        const int m0 = (blockIdx.x * 2 + mt) * 16;
        if (m0 >= NN) break;
        int row = m0 + c;
        if (row > NN - 1) row = NN - 1;
        bf16x8 afrag[4];
        #pragma unroll
        for (int kc = 0; kc < 4; ++kc) {
            const float* xp = x + (size_t)row * F_IN + kc * 32 + q * 8;
            float4 p0 = *(const float4*)xp;
            float4 p1 = *(const float4*)(xp + 4);
            bf16x8 aa;
            aa[0] = (short)f2bf(p0.x); aa[1] = (short)f2bf(p0.y);
            aa[2] = (short)f2bf(p0.z); aa[3] = (short)f2bf(p0.w);
            aa[4] = (short)f2bf(p1.x); aa[5] = (short)f2bf(p1.y);
            aa[6] = (short)f2bf(p1.z); aa[7] = (short)f2bf(p1.w);
            afrag[kc] = aa;
        }
        f32x4 acc0 = {0.f, 0.f, 0.f, 0.f};
        f32x4 acc1 = {0.f, 0.f, 0.f, 0.f};
        #pragma unroll
        for (int kc = 0; kc < 4; ++kc) {
            acc0 = __builtin_amdgcn_mfma_f32_16x16x32_bf16(afrag[kc], bfrag[0][kc], acc0, 0, 0, 0);
            acc1 = __builtin_amdgcn_mfma_f32_16x16x32_bf16(afrag[kc], bfrag[1][kc], acc1, 0, 0, 0);
        }
        #pragma unroll
        for (int r = 0; r < 4; ++r) {
            const int ro = m0 + q * 4 + r;
            float s0 = acc0[r] * as0, s1 = acc1[r] * as1;
            float d0 = acc0[r] * ad0, d1 = acc1[r] * ad1;
            #pragma unroll
            for (int m = 1; m <= 8; m <<= 1) {
                s0 += __shfl_xor(s0, m); s1 += __shfl_xor(s1, m);
                d0 += __shfl_xor(d0, m); d1 += __shfl_xor(d1, m);
            }
            if (ro < NN) {
                h1t[((size_t)h0 * NN + ro) * HID + c] = f2bf(acc0[r]);
                h1t[((size_t)h1 * NN + ro) * HID + c] = f2bf(acc1[r]);
                if (c == 0) {
                    es_t[(size_t)h0 * NN + ro] = s0;
                    es_t[(size_t)h1 * NN + ro] = s1;
                    ed_t[(size_t)h0 * NN + ro] = d0;
                    ed_t[(size_t)h1 * NN + ro] = d1;
                }
            }
        }
    }
}

// ---------------- CSR build (real edges only; self-loops handled in scan3) ----------------
__global__ void count_kernel(const int* __restrict__ ei, int* __restrict__ deg) {
    int base = (blockIdx.x * blockDim.x + threadIdx.x) * 4;
    if (base >= EE) return;
    int4 d4 = *(const int4*)(ei + EE + base);
    atomicAdd(&deg[d4.x], 1);
    atomicAdd(&deg[d4.y], 1);
    atomicAdd(&deg[d4.z], 1);
    atomicAdd(&deg[d4.w], 1);
}

// exclusive scan over (deg[i] + 1)  [+1 = self-loop]
__global__ void scan1_kernel(const int* __restrict__ deg, int* __restrict__ rowptr,
                             int* __restrict__ bsum) {
    __shared__ int sh[256];
    const int tid = threadIdx.x;
    const int base = blockIdx.x * 1024 + tid * 4;
    int v[4], s[4];
    #pragma unroll
    for (int j = 0; j < 4; ++j) v[j] = (base + j < NN) ? (deg[base + j] + 1) : 0;
    s[0] = v[0]; s[1] = s[0] + v[1]; s[2] = s[1] + v[2]; s[3] = s[2] + v[3];
    int T = s[3];
    sh[tid] = T;
    __syncthreads();
    for (int off = 1; off < 256; off <<= 1) {
        int xv = (tid >= off) ? sh[tid - off] : 0;
        __syncthreads();
        sh[tid] += xv;
        __syncthreads();
    }
    int excl = sh[tid] - T;
    #pragma unroll
    for (int j = 0; j < 4; ++j)
        if (base + j < NN) rowptr[base + j] = excl + s[j] - v[j];
    if (tid == 255) bsum[blockIdx.x] = sh[255];
}

__global__ void scan2_kernel(int* __restrict__ bsum, int nchunks) {
    __shared__ int sh[64];
    const int tid = threadIdx.x;
    int v = (tid < nchunks) ? bsum[tid] : 0;
    sh[tid] = v;
    __syncthreads();
    for (int off = 1; off < 64; off <<= 1) {
        int xv = (tid >= off) ? sh[tid - off] : 0;
        __syncthreads();
        sh[tid] += xv;
        __syncthreads();
    }
    if (tid < nchunks) bsum[tid] = sh[tid] - v;  // exclusive
}

// finalize rowptr; self-loop at slot rowptr[i]; cursor starts past it; deg -> total cnt
__global__ void scan3_kernel(int* __restrict__ rowptr, const int* __restrict__ bsum,
                             int* __restrict__ cursor, unsigned short* __restrict__ csr,
                             int* __restrict__ deg) {
    int i = blockIdx.x * blockDim.x + threadIdx.x;
    if (i >= NN) return;
    int rp = rowptr[i] + bsum[i >> 10];
    rowptr[i] = rp;
    cursor[i] = rp + 1;
    csr[rp] = (unsigned short)i;  // self-loop first
    deg[i] += 1;                  // total incoming count incl. self-loop
}

// scatter real edges: 4 per thread, int4 loads, ushort payloads
__global__ void fill_kernel(const int* __restrict__ ei, int* __restrict__ cursor,
                            unsigned short* __restrict__ csr) {
    int base = (blockIdx.x * blockDim.x + threadIdx.x) * 4;
    if (base >= EE) return;
    int4 s4 = *(const int4*)(ei + base);
    int4 d4 = *(const int4*)(ei + EE + base);
    int p0 = atomicAdd(&cursor[d4.x], 1);
    int p1 = atomicAdd(&cursor[d4.y], 1);
    int p2 = atomicAdd(&cursor[d4.z], 1);
    int p3 = atomicAdd(&cursor[d4.w], 1);
    csr[p0] = (unsigned short)s4.x;
    csr[p1] = (unsigned short)s4.y;
    csr[p2] = (unsigned short)s4.z;
    csr[p3] = (unsigned short)s4.w;
}

// ---------------- layer-1 aggregation: head-sliced, XCD-local L2 working set ----------
// head = blockIdx & 7 (XCD round-robin heuristic); 4 waves = 4 dst nodes.
// Wave = 8 edge-groups x 8 lanes; lane owns ch 2l,2l+1. Group g: edges g, g+8, ...
// hmid stored bf16 [NN][128].
__global__ void agg1_kernel(const unsigned short* __restrict__ h1t,
                            const float* __restrict__ es_t, const float* __restrict__ ed_t,
                            const int* __restrict__ rowptr, const int* __restrict__ deg,
                            const unsigned short* __restrict__ csr,
                            const float* __restrict__ b1, unsigned short* __restrict__ hmidb) {
    const int h = blockIdx.x & 7;
    const int d = (blockIdx.x >> 3) * 4 + (threadIdx.x >> 6);
    const int lane = threadIdx.x & 63;
    const int g = lane >> 3;
    const int l = lane & 7;
    const unsigned short* hb = h1t + (size_t)h * NN * HID;
    const float* es = es_t + (size_t)h * NN;
    const float ed = ed_t[(size_t)h * NN + d];
    const int start = rowptr[d];
    const int cnt = deg[d];

    float denom = 0.f, acc0 = 0.f, acc1 = 0.f;
    int i = g;
    for (; i + 8 < cnt; i += 16) {
        int s0 = csr[start + i];
        int s1 = csr[start + i + 8];
        float e0 = es[s0], e1 = es[s1];
        unsigned g0 = *(const unsigned*)(hb + (size_t)s0 * HID + 2 * l);
        unsigned g1 = *(const unsigned*)(hb + (size_t)s1 * HID + 2 * l);
        float w0 = __expf(lrelu(e0 + ed));
        float w1 = __expf(lrelu(e1 + ed));
        denom += w0 + w1;
        acc0 += w0 * bflo(g0) + w1 * bflo(g1);
        acc1 += w0 * bfhi(g0) + w1 * bfhi(g1);
    }
    if (i < cnt) {
        int s0 = csr[start + i];
        float e0 = es[s0];
        unsigned g0 = *(const unsigned*)(hb + (size_t)s0 * HID + 2 * l);
        float w0 = __expf(lrelu(e0 + ed));
        denom += w0;
        acc0 += w0 * bflo(g0);
        acc1 += w0 * bfhi(g0);
    }
    denom += __shfl_xor(denom, 8); denom += __shfl_xor(denom, 16); denom += __shfl_xor(denom, 32);
    acc0  += __shfl_xor(acc0, 8);  acc0  += __shfl_xor(acc0, 16);  acc0  += __shfl_xor(acc0, 32);
    acc1  += __shfl_xor(acc1, 8);  acc1  += __shfl_xor(acc1, 16);  acc1  += __shfl_xor(acc1, 32);
    if (g == 0) {
        const float inv = 1.f / (denom + 1e-16f);
        float o0 = acc0 * inv + b1[h * HID + 2 * l];
        float o1 = acc1 * inv + b1[h * HID + 2 * l + 1];
        o0 = (o0 > 0.f) ? o0 : expm1f(o0);
        o1 = (o1 > 0.f) ? o1 : expm1f(o1);
        unsigned pk = (unsigned)f2bf(o0) | ((unsigned)f2bf(o1) << 16);
        *(unsigned*)(hmidb + (size_t)d * C1 + h * HID + 2 * l) = pk;
    }
}

// ---------------- GEMM2 (MFMA bf16, bf16 input) + fused elogit2 ----------------
__global__ void gemm2_kernel(const unsigned short* __restrict__ hmidb, const float* __restrict__ W2,
                             const float* __restrict__ a_src, const float* __restrict__ a_dst,
                             unsigned short* __restrict__ h2b,
                             float* __restrict__ es2, float* __restrict__ ed2) {
    const int tid = threadIdx.x;
    const int w = tid >> 6, lane = tid & 63;
    const int q = lane >> 4, c = lane & 15;

    bf16x8 bfrag[3][4];
    float a2s[3], a2d[3];
    #pragma unroll
    for (int nt = 0; nt < 3; ++nt) {
        const int col = nt * 16 + c;
        const bool cv = col < CLASSES;
        a2s[nt] = cv ? a_src[col] : 0.f;
        a2d[nt] = cv ? a_dst[col] : 0.f;
        #pragma unroll
        for (int kc = 0; kc < 4; ++kc) {
            const int k0 = kc * 32 + q * 8;
            bf16x8 bb;
            #pragma unroll
            for (int j = 0; j < 8; ++j)
                bb[j] = cv ? (short)f2bf(W2[(size_t)(k0 + j) * CLASSES + col]) : (short)0;
            bfrag[nt][kc] = bb;
        }
    }

    const int m0 = (blockIdx.x * 4 + w) * 16;
    if (m0 >= NN) return;
    int row = m0 + c;
    if (row > NN - 1) row = NN - 1;
    bf16x8 afrag[4];
    #pragma unroll
    for (int kc = 0; kc < 4; ++kc)
        afrag[kc] = *(const bf16x8*)(hmidb + (size_t)row * F_IN + kc * 32 + q * 8);
    f32x4 acc[3] = {{0.f,0.f,0.f,0.f},{0.f,0.f,0.f,0.f},{0.f,0.f,0.f,0.f}};
    #pragma unroll
    for (int kc = 0; kc < 4; ++kc) {
        acc[0] = __builtin_amdgcn_mfma_f32_16x16x32_bf16(afrag[kc], bfrag[0][kc], acc[0], 0, 0, 0);
        acc[1] = __builtin_amdgcn_mfma_f32_16x16x32_bf16(afrag[kc], bfrag[1][kc], acc[1], 0, 0, 0);
        acc[2] = __builtin_amdgcn_mfma_f32_16x16x32_bf16(afrag[kc], bfrag[2][kc], acc[2], 0, 0, 0);
    }
    #pragma unroll
    for (int r = 0; r < 4; ++r) {
        const int ro = m0 + q * 4 + r;
        float ss = acc[0][r] * a2s[0] + acc[1][r] * a2s[1] + acc[2][r] * a2s[2];
        float sd = acc[0][r] * a2d[0] + acc[1][r] * a2d[1] + acc[2][r] * a2d[2];
        #pragma unroll
        for (int m = 1; m <= 8; m <<= 1) {
            ss += __shfl_xor(ss, m);
            sd += __shfl_xor(sd, m);
        }
        if (ro < NN && c == 0) {
            es2[ro] = ss;
            ed2[ro] = sd;
        }
    }
    #pragma unroll
    for (int nt = 0; nt < 3; ++nt) {
        const int col = nt * 16 + c;
        if (col >= CLASSES) continue;
        #pragma unroll
        for (int r = 0; r < 4; ++r) {
            const int ro = m0 + q * 4 + r;
            if (ro < NN) h2b[(size_t)ro * CLASSES + col] = f2bf(acc[nt][r]);
        }
    }
}

// ---------------- layer-2 aggregation -> output: scalar row bases, 8x unroll ----------------
__global__ void agg2_kernel(const unsigned short* __restrict__ h2b,
                            const float* __restrict__ e_src, const float* __restrict__ e_dst,
                            const int* __restrict__ rowptr, const int* __restrict__ deg,
                            const unsigned short* __restrict__ csr,
                            const float* __restrict__ b2, float* __restrict__ out) {
    const int d = blockIdx.x * 4 + (threadIdx.x >> 6);
    const int lane = threadIdx.x & 63;
    const int c = (lane < CLASSES) ? lane : (CLASSES - 1);
    const float ed = e_dst[d];
    const int start = rowptr[d];
    const int cnt = deg[d];

    float denom = 0.f, acc = 0.f;
    int i = 0;
    for (; i + 8 <= cnt; i += 8) {
        int s[8];
        #pragma unroll
        for (int k = 0; k < 8; ++k)
            s[k] = __builtin_amdgcn_readfirstlane((int)csr[start + i + k]);
        unsigned short g[8];
        float es[8];
        #pragma unroll
        for (int k = 0; k < 8; ++k) {
            g[k]  = h2b[(size_t)s[k] * CLASSES + c];
            es[k] = e_src[s[k]];
        }
        #pragma unroll
        for (int k = 0; k < 8; ++k) {
            float w = __expf(lrelu(es[k] + ed));
            denom += w;
            acc += w * __uint_as_float(((unsigned)g[k]) << 16);
        }
    }
    for (; i < cnt; ++i) {
        int s0 = __builtin_amdgcn_readfirstlane((int)csr[start + i]);
        unsigned short g0 = h2b[(size_t)s0 * CLASSES + c];
        float w = __expf(lrelu(e_src[s0] + ed));
        denom += w;
        acc += w * __uint_as_float(((unsigned)g0) << 16);
    }
    if (lane < CLASSES)
        out[(size_t)d * CLASSES + lane] = acc / (denom + 1e-16f) + b2[lane];
}

extern "C" void kernel_launch(void* const* d_in, const int* in_sizes, int n_in,
                              void* d_out, int out_size, void* d_ws, size_t ws_size,
                              hipStream_t stream) {
    const float* x      = (const float*)d_in[0];
    const int*   ei     = (const int*)d_in[1];
    const float* W1     = (const float*)d_in[2];
    const float* a_src1 = (const float*)d_in[3];
    const float* a_dst1 = (const float*)d_in[4];
    const float* b1     = (const float*)d_in[5];
    const float* W2     = (const float*)d_in[6];
    const float* a_src2 = (const float*)d_in[7];
    const float* a_dst2 = (const float*)d_in[8];
    const float* b2     = (const float*)d_in[9];
    float* out = (float*)d_out;

    char* ws = (char*)d_ws;
    size_t off = 0;
    auto alloc = [&](size_t bytes) { char* p = ws + off; off += (bytes + 255) & ~(size_t)255; return p; };
    unsigned short* h1t   = (unsigned short*)alloc((size_t)NN * C1 * 2);
    unsigned short* hmidb = (unsigned short*)alloc((size_t)NN * C1 * 2);
    unsigned short* h2b   = (unsigned short*)alloc((size_t)NN * CLASSES * 2);
    float* es_t   = (float*)alloc((size_t)NN * HEADS * 4);
    float* ed_t   = (float*)alloc((size_t)NN * HEADS * 4);
    float* es2    = (float*)alloc((size_t)NN * 4);
    float* ed2    = (float*)alloc((size_t)NN * 4);
    int*   deg    = (int*)alloc((size_t)NN * 4);
    int*   rowptr = (int*)alloc((size_t)NN * 4);
    int*   cursor = (int*)alloc((size_t)NN * 4);
    unsigned short* csr = (unsigned short*)alloc((size_t)ET * 2);
    int*   bsum   = (int*)alloc(256 * 4);

    hipMemsetAsync(deg, 0, (size_t)NN * 4, stream);

    gemm1_kernel<<<(NN + 31) / 32, 256, 0, stream>>>(x, W1, a_src1, a_dst1, h1t, es_t, ed_t);

    count_kernel<<<(EE / 4 + 255) / 256, 256, 0, stream>>>(ei, deg);
    const int nchunks = (NN + 1023) / 1024;  // 49
    scan1_kernel<<<nchunks, 256, 0, stream>>>(deg, rowptr, bsum);
    scan2_kernel<<<1, 64, 0, stream>>>(bsum, nchunks);
    scan3_kernel<<<(NN + 255) / 256, 256, 0, stream>>>(rowptr, bsum, cursor, csr, deg);
    fill_kernel<<<(EE / 4 + 255) / 256, 256, 0, stream>>>(ei, cursor, csr);

    agg1_kernel<<<(NN / 4) * 8, 256, 0, stream>>>(h1t, es_t, ed_t, rowptr, deg, csr, b1, hmidb);

    gemm2_kernel<<<(NN + 63) / 64, 256, 0, stream>>>(hmidb, W2, a_src2, a_dst2, h2b, es2, ed2);

    agg2_kernel<<<NN / 4, 256, 0, stream>>>(h2b, es2, ed2, rowptr, deg, csr, b2, out);
}

// Round 11
// 306.183 us; speedup vs baseline: 1.1621x; 1.1621x over previous
//
#include <hip/hip_runtime.h>
#include <math.h>

#define NN 50000
#define EE 800000
#define ET (EE + NN)      // edges + self loops
#define F_IN 128
#define HEADS 8
#define HID 16
#define C1 (HEADS * HID)  // 128
#define CLASSES 40
#define NEG_SLOPE 0.2f

typedef __attribute__((ext_vector_type(8))) short bf16x8;
typedef __attribute__((ext_vector_type(4))) float f32x4;

__device__ __forceinline__ unsigned short f2bf(float f) {
    unsigned u = __float_as_uint(f);
    unsigned r = (u + 0x7fffu + ((u >> 16) & 1u)) >> 16;  // round-to-nearest-even
    return (unsigned short)r;
}
__device__ __forceinline__ float lrelu(float a) {
    return (a > 0.f) ? a : NEG_SLOPE * a;
}
__device__ __forceinline__ float bflo(unsigned u) { return __uint_as_float(u << 16); }
__device__ __forceinline__ float bfhi(unsigned u) { return __uint_as_float(u & 0xffff0000u); }

// ---------------- GEMM1 (MFMA bf16) + fused elogit1 ----------------
// h1t layout: [HEADS][NN][HID] bf16. es_t/ed_t: [HEADS][NN] fp32.
__global__ void gemm1_kernel(const float* __restrict__ x, const float* __restrict__ W1,
                             const float* __restrict__ a_src, const float* __restrict__ a_dst,
                             unsigned short* __restrict__ h1t,
                             float* __restrict__ es_t, float* __restrict__ ed_t) {
    const int tid = threadIdx.x;
    const int w = tid >> 6, lane = tid & 63;
    const int q = lane >> 4, c = lane & 15;
    const int h0 = 2 * w, h1 = 2 * w + 1;

    bf16x8 bfrag[2][4];
    #pragma unroll
    for (int nt = 0; nt < 2; ++nt) {
        const int col = w * 32 + nt * 16 + c;
        #pragma unroll
        for (int kc = 0; kc < 4; ++kc) {
            const int k0 = kc * 32 + q * 8;
            bf16x8 bb;
            #pragma unroll
            for (int j = 0; j < 8; ++j)
                bb[j] = (short)f2bf(W1[(size_t)(k0 + j) * C1 + col]);
            bfrag[nt][kc] = bb;
        }
    }
    const float as0 = a_src[h0 * HID + c], as1 = a_src[h1 * HID + c];
    const float ad0 = a_dst[h0 * HID + c], ad1 = a_dst[h1 * HID + c];

    #pragma unroll
    for (int mt = 0; mt < 2; ++mt) {
        const int m0 = (blockIdx.x * 2 + mt) * 16;
        if (m0 >= NN) break;
        int row = m0 + c;
        if (row > NN - 1) row = NN - 1;
        bf16x8 afrag[4];
        #pragma unroll
        for (int kc = 0; kc < 4; ++kc) {
            const float* xp = x + (size_t)row * F_IN + kc * 32 + q * 8;
            float4 p0 = *(const float4*)xp;
            float4 p1 = *(const float4*)(xp + 4);
            bf16x8 aa;
            aa[0] = (short)f2bf(p0.x); aa[1] = (short)f2bf(p0.y);
            aa[2] = (short)f2bf(p0.z); aa[3] = (short)f2bf(p0.w);
            aa[4] = (short)f2bf(p1.x); aa[5] = (short)f2bf(p1.y);
            aa[6] = (short)f2bf(p1.z); aa[7] = (short)f2bf(p1.w);
            afrag[kc] = aa;
        }
        f32x4 acc0 = {0.f, 0.f, 0.f, 0.f};
        f32x4 acc1 = {0.f, 0.f, 0.f, 0.f};
        #pragma unroll
        for (int kc = 0; kc < 4; ++kc) {
            acc0 = __builtin_amdgcn_mfma_f32_16x16x32_bf16(afrag[kc], bfrag[0][kc], acc0, 0, 0, 0);
            acc1 = __builtin_amdgcn_mfma_f32_16x16x32_bf16(afrag[kc], bfrag[1][kc], acc1, 0, 0, 0);
        }
        #pragma unroll
        for (int r = 0; r < 4; ++r) {
            const int ro = m0 + q * 4 + r;
            float s0 = acc0[r] * as0, s1 = acc1[r] * as1;
            float d0 = acc0[r] * ad0, d1 = acc1[r] * ad1;
            #pragma unroll
            for (int m = 1; m <= 8; m <<= 1) {
                s0 += __shfl_xor(s0, m); s1 += __shfl_xor(s1, m);
                d0 += __shfl_xor(d0, m); d1 += __shfl_xor(d1, m);
            }
            if (ro < NN) {
                h1t[((size_t)h0 * NN + ro) * HID + c] = f2bf(acc0[r]);
                h1t[((size_t)h1 * NN + ro) * HID + c] = f2bf(acc1[r]);
                if (c == 0) {
                    es_t[(size_t)h0 * NN + ro] = s0;
                    es_t[(size_t)h1 * NN + ro] = s1;
                    ed_t[(size_t)h0 * NN + ro] = d0;
                    ed_t[(size_t)h1 * NN + ro] = d1;
                }
            }
        }
    }
}

// ---------------- CSR build (real edges only; self-loops handled in scan3) ----------------
__global__ void count_kernel(const int* __restrict__ ei, int* __restrict__ deg) {
    int base = (blockIdx.x * blockDim.x + threadIdx.x) * 4;
    if (base >= EE) return;
    int4 d4 = *(const int4*)(ei + EE + base);
    atomicAdd(&deg[d4.x], 1);
    atomicAdd(&deg[d4.y], 1);
    atomicAdd(&deg[d4.z], 1);
    atomicAdd(&deg[d4.w], 1);
}

// exclusive scan over (deg[i] + 1)  [+1 = self-loop]
__global__ void scan1_kernel(const int* __restrict__ deg, int* __restrict__ rowptr,
                             int* __restrict__ bsum) {
    __shared__ int sh[256];
    const int tid = threadIdx.x;
    const int base = blockIdx.x * 1024 + tid * 4;
    int v[4], s[4];
    #pragma unroll
    for (int j = 0; j < 4; ++j) v[j] = (base + j < NN) ? (deg[base + j] + 1) : 0;
    s[0] = v[0]; s[1] = s[0] + v[1]; s[2] = s[1] + v[2]; s[3] = s[2] + v[3];
    int T = s[3];
    sh[tid] = T;
    __syncthreads();
    for (int off = 1; off < 256; off <<= 1) {
        int xv = (tid >= off) ? sh[tid - off] : 0;
        __syncthreads();
        sh[tid] += xv;
        __syncthreads();
    }
    int excl = sh[tid] - T;
    #pragma unroll
    for (int j = 0; j < 4; ++j)
        if (base + j < NN) rowptr[base + j] = excl + s[j] - v[j];
    if (tid == 255) bsum[blockIdx.x] = sh[255];
}

__global__ void scan2_kernel(int* __restrict__ bsum, int nchunks) {
    __shared__ int sh[64];
    const int tid = threadIdx.x;
    int v = (tid < nchunks) ? bsum[tid] : 0;
    sh[tid] = v;
    __syncthreads();
    for (int off = 1; off < 64; off <<= 1) {
        int xv = (tid >= off) ? sh[tid - off] : 0;
        __syncthreads();
        sh[tid] += xv;
        __syncthreads();
    }
    if (tid < nchunks) bsum[tid] = sh[tid] - v;  // exclusive
}

// finalize rowptr; self-loop at slot rowptr[i]; cursor starts past it; deg -> total cnt
__global__ void scan3_kernel(int* __restrict__ rowptr, const int* __restrict__ bsum,
                             int* __restrict__ cursor, unsigned short* __restrict__ csr,
                             int* __restrict__ deg) {
    int i = blockIdx.x * blockDim.x + threadIdx.x;
    if (i >= NN) return;
    int rp = rowptr[i] + bsum[i >> 10];
    rowptr[i] = rp;
    cursor[i] = rp + 1;
    csr[rp] = (unsigned short)i;  // self-loop first
    deg[i] += 1;                  // total incoming count incl. self-loop
}

// scatter real edges: 4 per thread, int4 loads, ushort payloads
__global__ void fill_kernel(const int* __restrict__ ei, int* __restrict__ cursor,
                            unsigned short* __restrict__ csr) {
    int base = (blockIdx.x * blockDim.x + threadIdx.x) * 4;
    if (base >= EE) return;
    int4 s4 = *(const int4*)(ei + base);
    int4 d4 = *(const int4*)(ei + EE + base);
    int p0 = atomicAdd(&cursor[d4.x], 1);
    int p1 = atomicAdd(&cursor[d4.y], 1);
    int p2 = atomicAdd(&cursor[d4.z], 1);
    int p3 = atomicAdd(&cursor[d4.w], 1);
    csr[p0] = (unsigned short)s4.x;
    csr[p1] = (unsigned short)s4.y;
    csr[p2] = (unsigned short)s4.z;
    csr[p3] = (unsigned short)s4.w;
}

// ---------------- layer-1 aggregation: head-sliced + node-grouped waves ----------
// head = blockIdx & 7 (XCD round-robin); block = 4 waves; wave = 8 node-groups x 8 lanes.
// Group owns one dst node: 8 lanes walk its edge list together, lane covers ch 2l,2l+1
// of the head's 16. No cross-lane reduction needed (denom identical in group).
__global__ void agg1_kernel(const unsigned short* __restrict__ h1t,
                            const float* __restrict__ es_t, const float* __restrict__ ed_t,
                            const int* __restrict__ rowptr, const int* __restrict__ deg,
                            const unsigned short* __restrict__ csr,
                            const float* __restrict__ b1, unsigned short* __restrict__ hmidb) {
    const int h = blockIdx.x & 7;
    const int wv = threadIdx.x >> 6;
    const int lane = threadIdx.x & 63;
    const int grp = lane >> 3;
    const int l = lane & 7;
    const int d = (blockIdx.x >> 3) * 32 + wv * 8 + grp;
    const bool valid = d < NN;
    const int dd = valid ? d : NN - 1;

    const unsigned short* hb = h1t + (size_t)h * NN * HID + 2 * l;
    const float* es = es_t + (size_t)h * NN;
    const float ed = ed_t[(size_t)h * NN + dd];
    const int start = rowptr[dd];
    const int cnt = deg[dd];

    float denom = 0.f, acc0 = 0.f, acc1 = 0.f;
    int i = 0;
    for (; i + 2 <= cnt; i += 2) {
        int s0 = csr[start + i];
        int s1 = csr[start + i + 1];
        float e0 = es[s0], e1 = es[s1];
        unsigned g0 = *(const unsigned*)(hb + (size_t)s0 * HID);
        unsigned g1 = *(const unsigned*)(hb + (size_t)s1 * HID);
        float w0 = __expf(lrelu(e0 + ed));
        float w1 = __expf(lrelu(e1 + ed));
        denom += w0 + w1;
        acc0 += w0 * bflo(g0) + w1 * bflo(g1);
        acc1 += w0 * bfhi(g0) + w1 * bfhi(g1);
    }
    if (i < cnt) {
        int s0 = csr[start + i];
        float e0 = es[s0];
        unsigned g0 = *(const unsigned*)(hb + (size_t)s0 * HID);
        float w0 = __expf(lrelu(e0 + ed));
        denom += w0;
        acc0 += w0 * bflo(g0);
        acc1 += w0 * bfhi(g0);
    }
    if (valid) {
        const float inv = 1.f / (denom + 1e-16f);
        float o0 = acc0 * inv + b1[h * HID + 2 * l];
        float o1 = acc1 * inv + b1[h * HID + 2 * l + 1];
        o0 = (o0 > 0.f) ? o0 : expm1f(o0);
        o1 = (o1 > 0.f) ? o1 : expm1f(o1);
        unsigned pk = (unsigned)f2bf(o0) | ((unsigned)f2bf(o1) << 16);
        *(unsigned*)(hmidb + (size_t)d * C1 + h * HID + 2 * l) = pk;
    }
}

// ---------------- GEMM2 (MFMA bf16, bf16 input) + fused elogit2 ----------------
__global__ void gemm2_kernel(const unsigned short* __restrict__ hmidb, const float* __restrict__ W2,
                             const float* __restrict__ a_src, const float* __restrict__ a_dst,
                             unsigned short* __restrict__ h2b,
                             float* __restrict__ es2, float* __restrict__ ed2) {
    const int tid = threadIdx.x;
    const int w = tid >> 6, lane = tid & 63;
    const int q = lane >> 4, c = lane & 15;

    bf16x8 bfrag[3][4];
    float a2s[3], a2d[3];
    #pragma unroll
    for (int nt = 0; nt < 3; ++nt) {
        const int col = nt * 16 + c;
        const bool cv = col < CLASSES;
        a2s[nt] = cv ? a_src[col] : 0.f;
        a2d[nt] = cv ? a_dst[col] : 0.f;
        #pragma unroll
        for (int kc = 0; kc < 4; ++kc) {
            const int k0 = kc * 32 + q * 8;
            bf16x8 bb;
            #pragma unroll
            for (int j = 0; j < 8; ++j)
                bb[j] = cv ? (short)f2bf(W2[(size_t)(k0 + j) * CLASSES + col]) : (short)0;
            bfrag[nt][kc] = bb;
        }
    }

    const int m0 = (blockIdx.x * 4 + w) * 16;
    if (m0 >= NN) return;
    int row = m0 + c;
    if (row > NN - 1) row = NN - 1;
    bf16x8 afrag[4];
    #pragma unroll
    for (int kc = 0; kc < 4; ++kc)
        afrag[kc] = *(const bf16x8*)(hmidb + (size_t)row * F_IN + kc * 32 + q * 8);
    f32x4 acc[3] = {{0.f,0.f,0.f,0.f},{0.f,0.f,0.f,0.f},{0.f,0.f,0.f,0.f}};
    #pragma unroll
    for (int kc = 0; kc < 4; ++kc) {
        acc[0] = __builtin_amdgcn_mfma_f32_16x16x32_bf16(afrag[kc], bfrag[0][kc], acc[0], 0, 0, 0);
        acc[1] = __builtin_amdgcn_mfma_f32_16x16x32_bf16(afrag[kc], bfrag[1][kc], acc[1], 0, 0, 0);
        acc[2] = __builtin_amdgcn_mfma_f32_16x16x32_bf16(afrag[kc], bfrag[2][kc], acc[2], 0, 0, 0);
    }
    #pragma unroll
    for (int r = 0; r < 4; ++r) {
        const int ro = m0 + q * 4 + r;
        float ss = acc[0][r] * a2s[0] + acc[1][r] * a2s[1] + acc[2][r] * a2s[2];
        float sd = acc[0][r] * a2d[0] + acc[1][r] * a2d[1] + acc[2][r] * a2d[2];
        #pragma unroll
        for (int m = 1; m <= 8; m <<= 1) {
            ss += __shfl_xor(ss, m);
            sd += __shfl_xor(sd, m);
        }
        if (ro < NN && c == 0) {
            es2[ro] = ss;
            ed2[ro] = sd;
        }
    }
    #pragma unroll
    for (int nt = 0; nt < 3; ++nt) {
        const int col = nt * 16 + c;
        if (col >= CLASSES) continue;
        #pragma unroll
        for (int r = 0; r < 4; ++r) {
            const int ro = m0 + q * 4 + r;
            if (ro < NN) h2b[(size_t)ro * CLASSES + col] = f2bf(acc[nt][r]);
        }
    }
}

// ---------------- layer-2 aggregation -> output: scalar row bases, 8x unroll ----------------
__global__ void agg2_kernel(const unsigned short* __restrict__ h2b,
                            const float* __restrict__ e_src, const float* __restrict__ e_dst,
                            const int* __restrict__ rowptr, const int* __restrict__ deg,
                            const unsigned short* __restrict__ csr,
                            const float* __restrict__ b2, float* __restrict__ out) {
    const int d = blockIdx.x * 4 + (threadIdx.x >> 6);
    const int lane = threadIdx.x & 63;
    const int c = (lane < CLASSES) ? lane : (CLASSES - 1);
    const float ed = e_dst[d];
    const int start = rowptr[d];
    const int cnt = deg[d];

    float denom = 0.f, acc = 0.f;
    int i = 0;
    for (; i + 8 <= cnt; i += 8) {
        int s[8];
        #pragma unroll
        for (int k = 0; k < 8; ++k)
            s[k] = __builtin_amdgcn_readfirstlane((int)csr[start + i + k]);
        unsigned short g[8];
        float es[8];
        #pragma unroll
        for (int k = 0; k < 8; ++k) {
            g[k]  = h2b[(size_t)s[k] * CLASSES + c];
            es[k] = e_src[s[k]];
        }
        #pragma unroll
        for (int k = 0; k < 8; ++k) {
            float w = __expf(lrelu(es[k] + ed));
            denom += w;
            acc += w * __uint_as_float(((unsigned)g[k]) << 16);
        }
    }
    for (; i < cnt; ++i) {
        int s0 = __builtin_amdgcn_readfirstlane((int)csr[start + i]);
        unsigned short g0 = h2b[(size_t)s0 * CLASSES + c];
        float w = __expf(lrelu(e_src[s0] + ed));
        denom += w;
        acc += w * __uint_as_float(((unsigned)g0) << 16);
    }
    if (lane < CLASSES)
        out[(size_t)d * CLASSES + lane] = acc / (denom + 1e-16f) + b2[lane];
}

extern "C" void kernel_launch(void* const* d_in, const int* in_sizes, int n_in,
                              void* d_out, int out_size, void* d_ws, size_t ws_size,
                              hipStream_t stream) {
    const float* x      = (const float*)d_in[0];
    const int*   ei     = (const int*)d_in[1];
    const float* W1     = (const float*)d_in[2];
    const float* a_src1 = (const float*)d_in[3];
    const float* a_dst1 = (const float*)d_in[4];
    const float* b1     = (const float*)d_in[5];
    const float* W2     = (const float*)d_in[6];
    const float* a_src2 = (const float*)d_in[7];
    const float* a_dst2 = (const float*)d_in[8];
    const float* b2     = (const float*)d_in[9];
    float* out = (float*)d_out;

    char* ws = (char*)d_ws;
    size_t off = 0;
    auto alloc = [&](size_t bytes) { char* p = ws + off; off += (bytes + 255) & ~(size_t)255; return p; };
    unsigned short* h1t   = (unsigned short*)alloc((size_t)NN * C1 * 2);
    unsigned short* hmidb = (unsigned short*)alloc((size_t)NN * C1 * 2);
    unsigned short* h2b   = (unsigned short*)alloc((size_t)NN * CLASSES * 2);
    float* es_t   = (float*)alloc((size_t)NN * HEADS * 4);
    float* ed_t   = (float*)alloc((size_t)NN * HEADS * 4);
    float* es2    = (float*)alloc((size_t)NN * 4);
    float* ed2    = (float*)alloc((size_t)NN * 4);
    int*   deg    = (int*)alloc((size_t)NN * 4);
    int*   rowptr = (int*)alloc((size_t)NN * 4);
    int*   cursor = (int*)alloc((size_t)NN * 4);
    unsigned short* csr = (unsigned short*)alloc((size_t)ET * 2);
    int*   bsum   = (int*)alloc(256 * 4);

    hipMemsetAsync(deg, 0, (size_t)NN * 4, stream);

    gemm1_kernel<<<(NN + 31) / 32, 256, 0, stream>>>(x, W1, a_src1, a_dst1, h1t, es_t, ed_t);

    count_kernel<<<(EE / 4 + 255) / 256, 256, 0, stream>>>(ei, deg);
    const int nchunks = (NN + 1023) / 1024;  // 49
    scan1_kernel<<<nchunks, 256, 0, stream>>>(deg, rowptr, bsum);
    scan2_kernel<<<1, 64, 0, stream>>>(bsum, nchunks);
    scan3_kernel<<<(NN + 255) / 256, 256, 0, stream>>>(rowptr, bsum, cursor, csr, deg);
    fill_kernel<<<(EE / 4 + 255) / 256, 256, 0, stream>>>(ei, cursor, csr);

    agg1_kernel<<<((NN + 31) / 32) * 8, 256, 0, stream>>>(h1t, es_t, ed_t, rowptr, deg, csr, b1, hmidb);

    gemm2_kernel<<<(NN + 63) / 64, 256, 0, stream>>>(hmidb, W2, a_src2, a_dst2, h2b, es2, ed2);

    agg2_kernel<<<NN / 4, 256, 0, stream>>>(h2b, es2, ed2, rowptr, deg, csr, b2, out);
}

// Round 12
// 299.545 us; speedup vs baseline: 1.1878x; 1.0222x over previous
//
#include <hip/hip_runtime.h>
#include <math.h>

#define NN 50000
#define EE 800000
#define ET (EE + NN)      // edges + self loops
#define F_IN 128
#define HEADS 8
#define HID 16
#define C1 (HEADS * HID)  // 128
#define CLASSES 40
#define NEG_SLOPE 0.2f

typedef __attribute__((ext_vector_type(8))) short bf16x8;
typedef __attribute__((ext_vector_type(4))) float f32x4;

__device__ __forceinline__ unsigned short f2bf(float f) {
    unsigned u = __float_as_uint(f);
    unsigned r = (u + 0x7fffu + ((u >> 16) & 1u)) >> 16;  // round-to-nearest-even
    return (unsigned short)r;
}
__device__ __forceinline__ float lrelu(float a) {
    return (a > 0.f) ? a : NEG_SLOPE * a;
}
__device__ __forceinline__ float bflo(unsigned u) { return __uint_as_float(u << 16); }
__device__ __forceinline__ float bfhi(unsigned u) { return __uint_as_float(u & 0xffff0000u); }

// ---------------- GEMM1 (MFMA bf16) + fused elogit1 ----------------
// h1t layout: [HEADS][NN][HID] bf16. es_t/ed_t: [HEADS][NN] fp32.
__global__ void gemm1_kernel(const float* __restrict__ x, const float* __restrict__ W1,
                             const float* __restrict__ a_src, const float* __restrict__ a_dst,
                             unsigned short* __restrict__ h1t,
                             float* __restrict__ es_t, float* __restrict__ ed_t) {
    const int tid = threadIdx.x;
    const int w = tid >> 6, lane = tid & 63;
    const int q = lane >> 4, c = lane & 15;
    const int h0 = 2 * w, h1 = 2 * w + 1;

    bf16x8 bfrag[2][4];
    #pragma unroll
    for (int nt = 0; nt < 2; ++nt) {
        const int col = w * 32 + nt * 16 + c;
        #pragma unroll
        for (int kc = 0; kc < 4; ++kc) {
            const int k0 = kc * 32 + q * 8;
            bf16x8 bb;
            #pragma unroll
            for (int j = 0; j < 8; ++j)
                bb[j] = (short)f2bf(W1[(size_t)(k0 + j) * C1 + col]);
            bfrag[nt][kc] = bb;
        }
    }
    const float as0 = a_src[h0 * HID + c], as1 = a_src[h1 * HID + c];
    const float ad0 = a_dst[h0 * HID + c], ad1 = a_dst[h1 * HID + c];

    #pragma unroll
    for (int mt = 0; mt < 2; ++mt) {
        const int m0 = (blockIdx.x * 2 + mt) * 16;
        if (m0 >= NN) break;
        int row = m0 + c;
        if (row > NN - 1) row = NN - 1;
        bf16x8 afrag[4];
        #pragma unroll
        for (int kc = 0; kc < 4; ++kc) {
            const float* xp = x + (size_t)row * F_IN + kc * 32 + q * 8;
            float4 p0 = *(const float4*)xp;
            float4 p1 = *(const float4*)(xp + 4);
            bf16x8 aa;
            aa[0] = (short)f2bf(p0.x); aa[1] = (short)f2bf(p0.y);
            aa[2] = (short)f2bf(p0.z); aa[3] = (short)f2bf(p0.w);
            aa[4] = (short)f2bf(p1.x); aa[5] = (short)f2bf(p1.y);
            aa[6] = (short)f2bf(p1.z); aa[7] = (short)f2bf(p1.w);
            afrag[kc] = aa;
        }
        f32x4 acc0 = {0.f, 0.f, 0.f, 0.f};
        f32x4 acc1 = {0.f, 0.f, 0.f, 0.f};
        #pragma unroll
        for (int kc = 0; kc < 4; ++kc) {
            acc0 = __builtin_amdgcn_mfma_f32_16x16x32_bf16(afrag[kc], bfrag[0][kc], acc0, 0, 0, 0);
            acc1 = __builtin_amdgcn_mfma_f32_16x16x32_bf16(afrag[kc], bfrag[1][kc], acc1, 0, 0, 0);
        }
        #pragma unroll
        for (int r = 0; r < 4; ++r) {
            const int ro = m0 + q * 4 + r;
            float s0 = acc0[r] * as0, s1 = acc1[r] * as1;
            float d0 = acc0[r] * ad0, d1 = acc1[r] * ad1;
            #pragma unroll
            for (int m = 1; m <= 8; m <<= 1) {
                s0 += __shfl_xor(s0, m); s1 += __shfl_xor(s1, m);
                d0 += __shfl_xor(d0, m); d1 += __shfl_xor(d1, m);
            }
            if (ro < NN) {
                h1t[((size_t)h0 * NN + ro) * HID + c] = f2bf(acc0[r]);
                h1t[((size_t)h1 * NN + ro) * HID + c] = f2bf(acc1[r]);
                if (c == 0) {
                    es_t[(size_t)h0 * NN + ro] = s0;
                    es_t[(size_t)h1 * NN + ro] = s1;
                    ed_t[(size_t)h0 * NN + ro] = d0;
                    ed_t[(size_t)h1 * NN + ro] = d1;
                }
            }
        }
    }
}

// ---------------- CSR build (real edges only; self-loops handled in scan3) ----------------
__global__ void count_kernel(const int* __restrict__ ei, int* __restrict__ deg) {
    int base = (blockIdx.x * blockDim.x + threadIdx.x) * 4;
    if (base >= EE) return;
    int4 d4 = *(const int4*)(ei + EE + base);
    atomicAdd(&deg[d4.x], 1);
    atomicAdd(&deg[d4.y], 1);
    atomicAdd(&deg[d4.z], 1);
    atomicAdd(&deg[d4.w], 1);
}

// exclusive scan over (deg[i] + 1)  [+1 = self-loop]
__global__ void scan1_kernel(const int* __restrict__ deg, int* __restrict__ rowptr,
                             int* __restrict__ bsum) {
    __shared__ int sh[256];
    const int tid = threadIdx.x;
    const int base = blockIdx.x * 1024 + tid * 4;
    int v[4], s[4];
    #pragma unroll
    for (int j = 0; j < 4; ++j) v[j] = (base + j < NN) ? (deg[base + j] + 1) : 0;
    s[0] = v[0]; s[1] = s[0] + v[1]; s[2] = s[1] + v[2]; s[3] = s[2] + v[3];
    int T = s[3];
    sh[tid] = T;
    __syncthreads();
    for (int off = 1; off < 256; off <<= 1) {
        int xv = (tid >= off) ? sh[tid - off] : 0;
        __syncthreads();
        sh[tid] += xv;
        __syncthreads();
    }
    int excl = sh[tid] - T;
    #pragma unroll
    for (int j = 0; j < 4; ++j)
        if (base + j < NN) rowptr[base + j] = excl + s[j] - v[j];
    if (tid == 255) bsum[blockIdx.x] = sh[255];
}

__global__ void scan2_kernel(int* __restrict__ bsum, int nchunks) {
    __shared__ int sh[64];
    const int tid = threadIdx.x;
    int v = (tid < nchunks) ? bsum[tid] : 0;
    sh[tid] = v;
    __syncthreads();
    for (int off = 1; off < 64; off <<= 1) {
        int xv = (tid >= off) ? sh[tid - off] : 0;
        __syncthreads();
        sh[tid] += xv;
        __syncthreads();
    }
    if (tid < nchunks) bsum[tid] = sh[tid] - v;  // exclusive
}

// finalize rowptr; self-loop at slot rowptr[i]; cursor starts past it; deg -> total cnt
__global__ void scan3_kernel(int* __restrict__ rowptr, const int* __restrict__ bsum,
                             int* __restrict__ cursor, unsigned short* __restrict__ csr,
                             int* __restrict__ deg) {
    int i = blockIdx.x * blockDim.x + threadIdx.x;
    if (i >= NN) return;
    int rp = rowptr[i] + bsum[i >> 10];
    rowptr[i] = rp;
    cursor[i] = rp + 1;
    csr[rp] = (unsigned short)i;  // self-loop first
    deg[i] += 1;                  // total incoming count incl. self-loop
}

// scatter real edges: 4 per thread, int4 loads, ushort payloads
__global__ void fill_kernel(const int* __restrict__ ei, int* __restrict__ cursor,
                            unsigned short* __restrict__ csr) {
    int base = (blockIdx.x * blockDim.x + threadIdx.x) * 4;
    if (base >= EE) return;
    int4 s4 = *(const int4*)(ei + base);
    int4 d4 = *(const int4*)(ei + EE + base);
    int p0 = atomicAdd(&cursor[d4.x], 1);
    int p1 = atomicAdd(&cursor[d4.y], 1);
    int p2 = atomicAdd(&cursor[d4.z], 1);
    int p3 = atomicAdd(&cursor[d4.w], 1);
    csr[p0] = (unsigned short)s4.x;
    csr[p1] = (unsigned short)s4.y;
    csr[p2] = (unsigned short)s4.z;
    csr[p3] = (unsigned short)s4.w;
}

// ---------------- layer-1 aggregation: head-sliced + node-grouped waves, 4x unroll ----
// head = blockIdx & 7 (XCD round-robin); block = 4 waves; wave = 8 node-groups x 8 lanes.
// Group owns one dst node: 8 lanes walk its edge list together, lane covers ch 2l,2l+1.
__global__ void agg1_kernel(const unsigned short* __restrict__ h1t,
                            const float* __restrict__ es_t, const float* __restrict__ ed_t,
                            const int* __restrict__ rowptr, const int* __restrict__ deg,
                            const unsigned short* __restrict__ csr,
                            const float* __restrict__ b1, unsigned short* __restrict__ hmidb) {
    const int h = blockIdx.x & 7;
    const int wv = threadIdx.x >> 6;
    const int lane = threadIdx.x & 63;
    const int grp = lane >> 3;
    const int l = lane & 7;
    const int d = (blockIdx.x >> 3) * 32 + wv * 8 + grp;
    const bool valid = d < NN;
    const int dd = valid ? d : NN - 1;

    const unsigned short* hb = h1t + (size_t)h * NN * HID + 2 * l;
    const float* es = es_t + (size_t)h * NN;
    const float ed = ed_t[(size_t)h * NN + dd];
    const int start = rowptr[dd];
    const int cnt = deg[dd];

    float denom = 0.f, acc0 = 0.f, acc1 = 0.f;
    int i = 0;
    for (; i + 4 <= cnt; i += 4) {
        int s0 = csr[start + i];
        int s1 = csr[start + i + 1];
        int s2 = csr[start + i + 2];
        int s3 = csr[start + i + 3];
        float e0 = es[s0], e1 = es[s1], e2 = es[s2], e3 = es[s3];
        unsigned g0 = *(const unsigned*)(hb + (size_t)s0 * HID);
        unsigned g1 = *(const unsigned*)(hb + (size_t)s1 * HID);
        unsigned g2 = *(const unsigned*)(hb + (size_t)s2 * HID);
        unsigned g3 = *(const unsigned*)(hb + (size_t)s3 * HID);
        float w0 = __expf(lrelu(e0 + ed));
        float w1 = __expf(lrelu(e1 + ed));
        float w2 = __expf(lrelu(e2 + ed));
        float w3 = __expf(lrelu(e3 + ed));
        denom += (w0 + w1) + (w2 + w3);
        acc0 += w0 * bflo(g0) + w1 * bflo(g1) + w2 * bflo(g2) + w3 * bflo(g3);
        acc1 += w0 * bfhi(g0) + w1 * bfhi(g1) + w2 * bfhi(g2) + w3 * bfhi(g3);
    }
    for (; i < cnt; ++i) {
        int s0 = csr[start + i];
        float e0 = es[s0];
        unsigned g0 = *(const unsigned*)(hb + (size_t)s0 * HID);
        float w0 = __expf(lrelu(e0 + ed));
        denom += w0;
        acc0 += w0 * bflo(g0);
        acc1 += w0 * bfhi(g0);
    }
    if (valid) {
        const float inv = 1.f / (denom + 1e-16f);
        float o0 = acc0 * inv + b1[h * HID + 2 * l];
        float o1 = acc1 * inv + b1[h * HID + 2 * l + 1];
        o0 = (o0 > 0.f) ? o0 : expm1f(o0);
        o1 = (o1 > 0.f) ? o1 : expm1f(o1);
        unsigned pk = (unsigned)f2bf(o0) | ((unsigned)f2bf(o1) << 16);
        *(unsigned*)(hmidb + (size_t)d * C1 + h * HID + 2 * l) = pk;
    }
}

// ---------------- GEMM2 (MFMA bf16, bf16 input) + fused elogit2 ----------------
__global__ void gemm2_kernel(const unsigned short* __restrict__ hmidb, const float* __restrict__ W2,
                             const float* __restrict__ a_src, const float* __restrict__ a_dst,
                             unsigned short* __restrict__ h2b,
                             float* __restrict__ es2, float* __restrict__ ed2) {
    const int tid = threadIdx.x;
    const int w = tid >> 6, lane = tid & 63;
    const int q = lane >> 4, c = lane & 15;

    bf16x8 bfrag[3][4];
    float a2s[3], a2d[3];
    #pragma unroll
    for (int nt = 0; nt < 3; ++nt) {
        const int col = nt * 16 + c;
        const bool cv = col < CLASSES;
        a2s[nt] = cv ? a_src[col] : 0.f;
        a2d[nt] = cv ? a_dst[col] : 0.f;
        #pragma unroll
        for (int kc = 0; kc < 4; ++kc) {
            const int k0 = kc * 32 + q * 8;
            bf16x8 bb;
            #pragma unroll
            for (int j = 0; j < 8; ++j)
                bb[j] = cv ? (short)f2bf(W2[(size_t)(k0 + j) * CLASSES + col]) : (short)0;
            bfrag[nt][kc] = bb;
        }
    }

    const int m0 = (blockIdx.x * 4 + w) * 16;
    if (m0 >= NN) return;
    int row = m0 + c;
    if (row > NN - 1) row = NN - 1;
    bf16x8 afrag[4];
    #pragma unroll
    for (int kc = 0; kc < 4; ++kc)
        afrag[kc] = *(const bf16x8*)(hmidb + (size_t)row * F_IN + kc * 32 + q * 8);
    f32x4 acc[3] = {{0.f,0.f,0.f,0.f},{0.f,0.f,0.f,0.f},{0.f,0.f,0.f,0.f}};
    #pragma unroll
    for (int kc = 0; kc < 4; ++kc) {
        acc[0] = __builtin_amdgcn_mfma_f32_16x16x32_bf16(afrag[kc], bfrag[0][kc], acc[0], 0, 0, 0);
        acc[1] = __builtin_amdgcn_mfma_f32_16x16x32_bf16(afrag[kc], bfrag[1][kc], acc[1], 0, 0, 0);
        acc[2] = __builtin_amdgcn_mfma_f32_16x16x32_bf16(afrag[kc], bfrag[2][kc], acc[2], 0, 0, 0);
    }
    #pragma unroll
    for (int r = 0; r < 4; ++r) {
        const int ro = m0 + q * 4 + r;
        float ss = acc[0][r] * a2s[0] + acc[1][r] * a2s[1] + acc[2][r] * a2s[2];
        float sd = acc[0][r] * a2d[0] + acc[1][r] * a2d[1] + acc[2][r] * a2d[2];
        #pragma unroll
        for (int m = 1; m <= 8; m <<= 1) {
            ss += __shfl_xor(ss, m);
            sd += __shfl_xor(sd, m);
        }
        if (ro < NN && c == 0) {
            es2[ro] = ss;
            ed2[ro] = sd;
        }
    }
    #pragma unroll
    for (int nt = 0; nt < 3; ++nt) {
        const int col = nt * 16 + c;
        if (col >= CLASSES) continue;
        #pragma unroll
        for (int r = 0; r < 4; ++r) {
            const int ro = m0 + q * 4 + r;
            if (ro < NN) h2b[(size_t)ro * CLASSES + col] = f2bf(acc[nt][r]);
        }
    }
}

// ---------------- layer-2 aggregation -> output: scalar row bases, 8x unroll ----------------
__global__ void agg2_kernel(const unsigned short* __restrict__ h2b,
                            const float* __restrict__ e_src, const float* __restrict__ e_dst,
                            const int* __restrict__ rowptr, const int* __restrict__ deg,
                            const unsigned short* __restrict__ csr,
                            const float* __restrict__ b2, float* __restrict__ out) {
    const int d = blockIdx.x * 4 + (threadIdx.x >> 6);
    const int lane = threadIdx.x & 63;
    const int c = (lane < CLASSES) ? lane : (CLASSES - 1);
    const float ed = e_dst[d];
    const int start = rowptr[d];
    const int cnt = deg[d];

    float denom = 0.f, acc = 0.f;
    int i = 0;
    for (; i + 8 <= cnt; i += 8) {
        int s[8];
        #pragma unroll
        for (int k = 0; k < 8; ++k)
            s[k] = __builtin_amdgcn_readfirstlane((int)csr[start + i + k]);
        unsigned short g[8];
        float es[8];
        #pragma unroll
        for (int k = 0; k < 8; ++k) {
            g[k]  = h2b[(size_t)s[k] * CLASSES + c];
            es[k] = e_src[s[k]];
        }
        #pragma unroll
        for (int k = 0; k < 8; ++k) {
            float w = __expf(lrelu(es[k] + ed));
            denom += w;
            acc += w * __uint_as_float(((unsigned)g[k]) << 16);
        }
    }
    for (; i < cnt; ++i) {
        int s0 = __builtin_amdgcn_readfirstlane((int)csr[start + i]);
        unsigned short g0 = h2b[(size_t)s0 * CLASSES + c];
        float w = __expf(lrelu(e_src[s0] + ed));
        denom += w;
        acc += w * __uint_as_float(((unsigned)g0) << 16);
    }
    if (lane < CLASSES)
        out[(size_t)d * CLASSES + lane] = acc / (denom + 1e-16f) + b2[lane];
}

extern "C" void kernel_launch(void* const* d_in, const int* in_sizes, int n_in,
                              void* d_out, int out_size, void* d_ws, size_t ws_size,
                              hipStream_t stream) {
    const float* x      = (const float*)d_in[0];
    const int*   ei     = (const int*)d_in[1];
    const float* W1     = (const float*)d_in[2];
    const float* a_src1 = (const float*)d_in[3];
    const float* a_dst1 = (const float*)d_in[4];
    const float* b1     = (const float*)d_in[5];
    const float* W2     = (const float*)d_in[6];
    const float* a_src2 = (const float*)d_in[7];
    const float* a_dst2 = (const float*)d_in[8];
    const float* b2     = (const float*)d_in[9];
    float* out = (float*)d_out;

    char* ws = (char*)d_ws;
    size_t off = 0;
    auto alloc = [&](size_t bytes) { char* p = ws + off; off += (bytes + 255) & ~(size_t)255; return p; };
    unsigned short* h1t   = (unsigned short*)alloc((size_t)NN * C1 * 2);
    unsigned short* hmidb = (unsigned short*)alloc((size_t)NN * C1 * 2);
    unsigned short* h2b   = (unsigned short*)alloc((size_t)NN * CLASSES * 2);
    float* es_t   = (float*)alloc((size_t)NN * HEADS * 4);
    float* ed_t   = (float*)alloc((size_t)NN * HEADS * 4);
    float* es2    = (float*)alloc((size_t)NN * 4);
    float* ed2    = (float*)alloc((size_t)NN * 4);
    int*   deg    = (int*)alloc((size_t)NN * 4);
    int*   rowptr = (int*)alloc((size_t)NN * 4);
    int*   cursor = (int*)alloc((size_t)NN * 4);
    unsigned short* csr = (unsigned short*)alloc((size_t)ET * 2);
    int*   bsum   = (int*)alloc(256 * 4);

    hipMemsetAsync(deg, 0, (size_t)NN * 4, stream);

    gemm1_kernel<<<(NN + 31) / 32, 256, 0, stream>>>(x, W1, a_src1, a_dst1, h1t, es_t, ed_t);

    count_kernel<<<(EE / 4 + 255) / 256, 256, 0, stream>>>(ei, deg);
    const int nchunks = (NN + 1023) / 1024;  // 49
    scan1_kernel<<<nchunks, 256, 0, stream>>>(deg, rowptr, bsum);
    scan2_kernel<<<1, 64, 0, stream>>>(bsum, nchunks);
    scan3_kernel<<<(NN + 255) / 256, 256, 0, stream>>>(rowptr, bsum, cursor, csr, deg);
    fill_kernel<<<(EE / 4 + 255) / 256, 256, 0, stream>>>(ei, cursor, csr);

    agg1_kernel<<<((NN + 31) / 32) * 8, 256, 0, stream>>>(h1t, es_t, ed_t, rowptr, deg, csr, b1, hmidb);

    gemm2_kernel<<<(NN + 63) / 64, 256, 0, stream>>>(hmidb, W2, a_src2, a_dst2, h2b, es2, ed2);

    agg2_kernel<<<NN / 4, 256, 0, stream>>>(h2b, es2, ed2, rowptr, deg, csr, b2, out);
}